// Round 1
// baseline (713.652 us; speedup 1.0000x reference)
//
#include <hip/hip_runtime.h>
#include <hip/hip_bf16.h>

typedef __bf16 bf16x8 __attribute__((ext_vector_type(8)));
typedef float f32x4 __attribute__((ext_vector_type(4)));
static_assert(sizeof(bf16x8) == 16, "bf16x8 must be 16B");

constexpr int S  = 2048;
constexpr int D  = 128;
constexpr int HQ = 32;
constexpr int W  = 1024;
// fold 1/sqrt(128) * log2(e) into Q so scores come out in log2 domain
constexpr float SCALE_L2E = 0.08838834764831845f * 1.4426950408889634f;

constexpr size_t O1 = (size_t)S * HQ * D;        // attn_weights offset  (8388608)
constexpr size_t O2 = O1 + (size_t)HQ * S * S;   // window offset        (142606336)

__global__ __launch_bounds__(256, 3)
void attn_fused(const float* __restrict__ Q, const float* __restrict__ K,
                const float* __restrict__ V, float* __restrict__ out)
{
    __shared__ __attribute__((aligned(16))) __bf16 Kt[64][136];   // K tile, padded pitch
    __shared__ __attribute__((aligned(16))) __bf16 Vt[128][72];   // V tile transposed [d][k]
    __shared__ __attribute__((aligned(16))) __bf16 Pst[4][16][72];// per-wave P strip

    const int bid = blockIdx.x;
    const int h   = bid >> 5;
    const int qt  = 31 - (bid & 31);      // big (diagonal-heavy) tiles first
    const int hkv = h >> 2;               // groups = 4
    const int q0  = qt << 6;

    const int tid  = threadIdx.x;
    const int wave = tid >> 6;
    const int lane = tid & 63;
    const int lo   = lane & 15;
    const int hi   = lane >> 4;

    const float* Qh = Q + (size_t)h   * S * D;
    const float* Kh = K + (size_t)hkv * S * D;
    const float* Vh = V + (size_t)hkv * S * D;

    const int qw0 = q0 + wave * 16;       // this wave's 16 q-rows

    // ---- Q fragments: row = lo, k-chunk = hi*8 + dc*32, pre-scaled, bf16 ----
    bf16x8 qf[4];
    {
        const float* qs = Qh + (size_t)(qw0 + lo) * D + hi * 8;
        #pragma unroll
        for (int dc = 0; dc < 4; ++dc) {
            float4 a = *reinterpret_cast<const float4*>(qs + dc * 32);
            float4 b = *reinterpret_cast<const float4*>(qs + dc * 32 + 4);
            bf16x8 f;
            f[0] = (__bf16)(a.x * SCALE_L2E); f[1] = (__bf16)(a.y * SCALE_L2E);
            f[2] = (__bf16)(a.z * SCALE_L2E); f[3] = (__bf16)(a.w * SCALE_L2E);
            f[4] = (__bf16)(b.x * SCALE_L2E); f[5] = (__bf16)(b.y * SCALE_L2E);
            f[6] = (__bf16)(b.z * SCALE_L2E); f[7] = (__bf16)(b.w * SCALE_L2E);
            qf[dc] = f;
        }
    }

    // ================= pass 1: row sums of exp2(scores) =================
    float lsum[4] = {0.f, 0.f, 0.f, 0.f};

    for (int kt = 0; kt <= qt; ++kt) {
        __syncthreads();
        {   // stage K tile -> LDS (bf16)
            const float* src = Kh + (size_t)(kt << 6) * D;
            #pragma unroll
            for (int i = 0; i < 8; ++i) {
                int idx = tid + i * 256;
                int r = idx >> 5, c = (idx & 31) * 4;
                float4 v = *reinterpret_cast<const float4*>(src + r * D + c);
                Kt[r][c + 0] = (__bf16)v.x; Kt[r][c + 1] = (__bf16)v.y;
                Kt[r][c + 2] = (__bf16)v.z; Kt[r][c + 3] = (__bf16)v.w;
            }
        }
        __syncthreads();
        const int kbase = kt << 6;
        #pragma unroll
        for (int cg = 0; cg < 4; ++cg) {
            f32x4 acc = {0.f, 0.f, 0.f, 0.f};
            #pragma unroll
            for (int dc = 0; dc < 4; ++dc) {
                bf16x8 kf = *reinterpret_cast<const bf16x8*>(&Kt[cg * 16 + lo][hi * 8 + dc * 32]);
                acc = __builtin_amdgcn_mfma_f32_16x16x32_bf16(qf[dc], kf, acc, 0, 0, 0);
            }
            const int k = kbase + cg * 16 + lo;
            #pragma unroll
            for (int r = 0; r < 4; ++r) {
                int q = qw0 + hi * 4 + r;
                lsum[r] += (k <= q) ? exp2f(acc[r]) : 0.f;
            }
        }
    }
    #pragma unroll
    for (int r = 0; r < 4; ++r) {   // reduce across the 16 lanes sharing hi
        float v = lsum[r];
        v += __shfl_xor(v, 1);
        v += __shfl_xor(v, 2);
        v += __shfl_xor(v, 4);
        v += __shfl_xor(v, 8);
        lsum[r] = 1.0f / v;          // now the reciprocal
    }

    // ================= pass 2: P writes + PV accumulate =================
    f32x4 oacc[8];
    #pragma unroll
    for (int i = 0; i < 8; ++i) oacc[i] = (f32x4){0.f, 0.f, 0.f, 0.f};

    const bool winrows = (q0 >= W);   // block-uniform

    for (int kt = 0; kt <= qt; ++kt) {
        __syncthreads();
        {   // stage K tile + transposed V tile
            const float* srcK = Kh + (size_t)(kt << 6) * D;
            const float* srcV = Vh + (size_t)(kt << 6) * D;
            #pragma unroll
            for (int i = 0; i < 8; ++i) {
                int idx = tid + i * 256;
                int r = idx >> 5, c = (idx & 31) * 4;
                float4 v = *reinterpret_cast<const float4*>(srcK + r * D + c);
                Kt[r][c + 0] = (__bf16)v.x; Kt[r][c + 1] = (__bf16)v.y;
                Kt[r][c + 2] = (__bf16)v.z; Kt[r][c + 3] = (__bf16)v.w;
                float4 w = *reinterpret_cast<const float4*>(srcV + r * D + c);
                Vt[c + 0][r] = (__bf16)w.x; Vt[c + 1][r] = (__bf16)w.y;
                Vt[c + 2][r] = (__bf16)w.z; Vt[c + 3][r] = (__bf16)w.w;
            }
        }
        __syncthreads();
        const int kbase = kt << 6;
        #pragma unroll
        for (int cg = 0; cg < 4; ++cg) {
            f32x4 acc = {0.f, 0.f, 0.f, 0.f};
            #pragma unroll
            for (int dc = 0; dc < 4; ++dc) {
                bf16x8 kf = *reinterpret_cast<const bf16x8*>(&Kt[cg * 16 + lo][hi * 8 + dc * 32]);
                acc = __builtin_amdgcn_mfma_f32_16x16x32_bf16(qf[dc], kf, acc, 0, 0, 0);
            }
            const int k = kbase + cg * 16 + lo;
            #pragma unroll
            for (int r = 0; r < 4; ++r) {
                const int q = qw0 + hi * 4 + r;
                float p = (k <= q) ? exp2f(acc[r]) * lsum[r] : 0.f;
                out[O1 + ((size_t)h * S + q) * S + k] = p;
                if (winrows)
                    out[O2 + ((size_t)h * W + (q - W)) * S + k] = p;
                Pst[wave][hi * 4 + r][cg * 16 + lo] = (__bf16)p;
            }
        }
        // PV: A = P strip (via LDS round trip), B = V^T from LDS
        #pragma unroll
        for (int kc = 0; kc < 2; ++kc) {
            bf16x8 pf = *reinterpret_cast<const bf16x8*>(&Pst[wave][lo][kc * 32 + hi * 8]);
            #pragma unroll
            for (int dg = 0; dg < 8; ++dg) {
                bf16x8 vf = *reinterpret_cast<const bf16x8*>(&Vt[dg * 16 + lo][kc * 32 + hi * 8]);
                oacc[dg] = __builtin_amdgcn_mfma_f32_16x16x32_bf16(pf, vf, oacc[dg], 0, 0, 0);
            }
        }
    }

    // ================= zero-fill the masked tiles (k-tiles > qt) =================
    {
        const int r0 = tid >> 4;          // 0..15
        const int c4 = (tid & 15) * 4;    // 0..60
        for (int kt = qt + 1; kt < 32; ++kt) {
            const int kbase = kt << 6;
            #pragma unroll
            for (int i = 0; i < 4; ++i) {
                const int q = q0 + r0 + i * 16;
                float4 z = {0.f, 0.f, 0.f, 0.f};
                *reinterpret_cast<float4*>(&out[O1 + ((size_t)h * S + q) * S + kbase + c4]) = z;
                if (winrows)
                    *reinterpret_cast<float4*>(&out[O2 + ((size_t)h * W + (q - W)) * S + kbase + c4]) = z;
            }
        }
    }

    // ================= write attn_output (S, HQ, D layout) =================
    #pragma unroll
    for (int dg = 0; dg < 8; ++dg) {
        #pragma unroll
        for (int r = 0; r < 4; ++r) {
            const int q = qw0 + hi * 4 + r;
            out[((size_t)q * HQ + h) * D + dg * 16 + lo] = oacc[dg][r];
        }
    }
}

extern "C" void kernel_launch(void* const* d_in, const int* in_sizes, int n_in,
                              void* d_out, int out_size, void* d_ws, size_t ws_size,
                              hipStream_t stream)
{
    const float* Q = (const float*)d_in[0];
    const float* K = (const float*)d_in[1];
    const float* V = (const float*)d_in[2];
    float* out = (float*)d_out;
    dim3 grid(HQ * (S / 64));   // 32 heads * 32 q-tiles = 1024 blocks
    dim3 block(256);
    hipLaunchKernelGGL(attn_fused, grid, block, 0, stream, Q, K, V, out);
}

// Round 2
// 401.694 us; speedup vs baseline: 1.7766x; 1.7766x over previous
//
#include <hip/hip_runtime.h>
#include <hip/hip_bf16.h>

typedef __bf16 bf16x8 __attribute__((ext_vector_type(8)));
typedef __bf16 bf16x4 __attribute__((ext_vector_type(4)));
typedef float f32x4 __attribute__((ext_vector_type(4)));
static_assert(sizeof(bf16x8) == 16, "bf16x8 must be 16B");

constexpr int S = 2048, D = 128, HQ = 32, W = 1024;
constexpr float SCALE_L2E = 0.08838834764831845f * 1.4426950408889634f;

constexpr size_t O1 = (size_t)S * HQ * D;        // attn_weights offset
constexpr size_t O2 = O1 + (size_t)HQ * S * S;   // window offset

// ---------------- kernel 0: K -> bf16, V -> bf16 transposed (in ws) ----------------
__global__ __launch_bounds__(256)
void prep_kernel(const float* __restrict__ K, const float* __restrict__ V,
                 __bf16* __restrict__ Kb, __bf16* __restrict__ Vtb)
{
    __shared__ __attribute__((aligned(16))) __bf16 Vs[128][72];   // pitch 144B (16B-mult)
    const int b   = blockIdx.x;
    const int hkv = b >> 5, kt = b & 31;
    const int tid = threadIdx.x;
    const float* Ks   = K + ((size_t)hkv * S + kt * 64) * D;
    const float* Vsrc = V + ((size_t)hkv * S + kt * 64) * D;
    __bf16* Kd = Kb + ((size_t)hkv * S + kt * 64) * D;
    #pragma unroll
    for (int i = 0; i < 8; ++i) {
        int idx = tid + i * 256;
        int r = idx >> 5, c = (idx & 31) * 4;
        float4 kv = *reinterpret_cast<const float4*>(Ks + r * D + c);
        bf16x4 k4 = {(__bf16)kv.x, (__bf16)kv.y, (__bf16)kv.z, (__bf16)kv.w};
        *reinterpret_cast<bf16x4*>(Kd + r * D + c) = k4;
        float4 vv = *reinterpret_cast<const float4*>(Vsrc + r * D + c);
        Vs[c + 0][r] = (__bf16)vv.x; Vs[c + 1][r] = (__bf16)vv.y;
        Vs[c + 2][r] = (__bf16)vv.z; Vs[c + 3][r] = (__bf16)vv.w;
    }
    __syncthreads();
    #pragma unroll
    for (int it = 0; it < 4; ++it) {
        int d = (tid >> 3) + it * 32;
        int slot = tid & 7;
        bf16x8 v = *reinterpret_cast<const bf16x8*>(&Vs[d][slot * 8]);
        *reinterpret_cast<bf16x8*>(Vtb + ((size_t)hkv * D + d) * S + kt * 64 + slot * 8) = v;
    }
}

// ---------------- kernel 1: row sums (reciprocals) of exp2(scores) ----------------
__global__ __launch_bounds__(256, 4)
void lsum_kernel(const float* __restrict__ Q, const __bf16* __restrict__ Kb,
                 float* __restrict__ lsr)
{
    __shared__ __attribute__((aligned(16))) char KtB[64 * 256];   // 16KB, swizzled
    const int bid = blockIdx.x;
    const int h   = bid >> 5;
    const int qt  = 31 - (((bid & 31) + h) & 31);   // diagonal load balance
    const int hkv = h >> 2;
    const int q0  = qt << 6;
    const int tid = threadIdx.x, wave = tid >> 6, lane = tid & 63;
    const int lo = lane & 15, hi = lane >> 4;
    const int qw0 = q0 + wave * 16;
    const __bf16* Kbh = Kb + (size_t)hkv * S * D;
    const float*  Qh  = Q  + (size_t)h   * S * D;

    bf16x8 qf[4];
    {
        const float* qs = Qh + (size_t)(qw0 + lo) * D + hi * 8;
        #pragma unroll
        for (int dc = 0; dc < 4; ++dc) {
            float4 a = *reinterpret_cast<const float4*>(qs + dc * 32);
            float4 b = *reinterpret_cast<const float4*>(qs + dc * 32 + 4);
            bf16x8 f;
            f[0] = (__bf16)(a.x * SCALE_L2E); f[1] = (__bf16)(a.y * SCALE_L2E);
            f[2] = (__bf16)(a.z * SCALE_L2E); f[3] = (__bf16)(a.w * SCALE_L2E);
            f[4] = (__bf16)(b.x * SCALE_L2E); f[5] = (__bf16)(b.y * SCALE_L2E);
            f[6] = (__bf16)(b.z * SCALE_L2E); f[7] = (__bf16)(b.w * SCALE_L2E);
            qf[dc] = f;
        }
    }

    float lsum[4] = {0.f, 0.f, 0.f, 0.f};
    for (int kt = 0; kt <= qt; ++kt) {
        __syncthreads();
        const int kbase = kt << 6;
        #pragma unroll
        for (int i = 0; i < 4; ++i) {
            int row = wave * 16 + i * 4 + (lane >> 4);
            int slot = lane & 15;
            bf16x8 v = *reinterpret_cast<const bf16x8*>(
                reinterpret_cast<const char*>(Kbh + (size_t)(kbase + row) * D) + slot * 16);
            *reinterpret_cast<bf16x8*>(KtB + row * 256 + ((slot * 16) ^ ((row & 7) << 4))) = v;
        }
        __syncthreads();
        #pragma unroll
        for (int cg = 0; cg < 4; ++cg) {
            f32x4 acc = {0.f, 0.f, 0.f, 0.f};
            const int row = cg * 16 + lo;
            const int swzr = (row & 7) << 4;
            #pragma unroll
            for (int dc = 0; dc < 4; ++dc) {
                bf16x8 kf = *reinterpret_cast<const bf16x8*>(
                    KtB + row * 256 + ((hi * 16 + dc * 64) ^ swzr));
                acc = __builtin_amdgcn_mfma_f32_16x16x32_bf16(qf[dc], kf, acc, 0, 0, 0);
            }
            const int k = kbase + cg * 16 + lo;
            #pragma unroll
            for (int r = 0; r < 4; ++r) {
                int q = qw0 + hi * 4 + r;
                lsum[r] += (k <= q) ? exp2f(acc[r]) : 0.f;
            }
        }
    }
    #pragma unroll
    for (int r = 0; r < 4; ++r) {
        float v = lsum[r];
        v += __shfl_xor(v, 1); v += __shfl_xor(v, 2);
        v += __shfl_xor(v, 4); v += __shfl_xor(v, 8);
        if (lo == 0) lsr[h * S + qw0 + hi * 4 + r] = 1.0f / v;
    }
}

// ---------------- kernel 2: P stores + window + PV + O ----------------
__global__ __launch_bounds__(256, 4)
void attn_main(const float* __restrict__ Q, const __bf16* __restrict__ Kb,
               const __bf16* __restrict__ Vtb, const float* __restrict__ lsr,
               float* __restrict__ out)
{
    __shared__ __attribute__((aligned(16))) char KtB[64 * 256];    // 16KB
    __shared__ __attribute__((aligned(16))) char VtB[128 * 128];   // 16KB (V^T, [d][k])
    __shared__ __attribute__((aligned(16))) char PsB[4 * 16 * 128];// 8KB per-wave P strips

    const int bid = blockIdx.x;
    const int h   = bid >> 5;
    const int qt  = 31 - (((bid & 31) + h) & 31);
    const int hkv = h >> 2;
    const int q0  = qt << 6;
    const int tid = threadIdx.x, wave = tid >> 6, lane = tid & 63;
    const int lo = lane & 15, hi = lane >> 4;
    const int qw0 = q0 + wave * 16;
    const bool winrows = (q0 >= W);

    const __bf16* Kbh = Kb  + (size_t)hkv * S * D;
    const __bf16* Vth = Vtb + (size_t)hkv * D * S;   // [d][k] pitch S
    const float*  Qh  = Q   + (size_t)h   * S * D;
    char* Ps = PsB + wave * 2048;

    bf16x8 qf[4];
    {
        const float* qs = Qh + (size_t)(qw0 + lo) * D + hi * 8;
        #pragma unroll
        for (int dc = 0; dc < 4; ++dc) {
            float4 a = *reinterpret_cast<const float4*>(qs + dc * 32);
            float4 b = *reinterpret_cast<const float4*>(qs + dc * 32 + 4);
            bf16x8 f;
            f[0] = (__bf16)(a.x * SCALE_L2E); f[1] = (__bf16)(a.y * SCALE_L2E);
            f[2] = (__bf16)(a.z * SCALE_L2E); f[3] = (__bf16)(a.w * SCALE_L2E);
            f[4] = (__bf16)(b.x * SCALE_L2E); f[5] = (__bf16)(b.y * SCALE_L2E);
            f[6] = (__bf16)(b.z * SCALE_L2E); f[7] = (__bf16)(b.w * SCALE_L2E);
            qf[dc] = f;
        }
    }

    float rcp[4];
    {
        float4 rc = *reinterpret_cast<const float4*>(lsr + h * S + qw0 + hi * 4);
        rcp[0] = rc.x; rcp[1] = rc.y; rcp[2] = rc.z; rcp[3] = rc.w;
    }

    f32x4 oacc[8];
    #pragma unroll
    for (int i = 0; i < 8; ++i) oacc[i] = (f32x4){0.f, 0.f, 0.f, 0.f};

    for (int kt = 0; kt <= qt; ++kt) {
        __syncthreads();
        const int kbase = kt << 6;
        // stage K (linear rows 256B, XOR-swizzled slots)
        #pragma unroll
        for (int i = 0; i < 4; ++i) {
            int row = wave * 16 + i * 4 + (lane >> 4);
            int slot = lane & 15;
            bf16x8 v = *reinterpret_cast<const bf16x8*>(
                reinterpret_cast<const char*>(Kbh + (size_t)(kbase + row) * D) + slot * 16);
            *reinterpret_cast<bf16x8*>(KtB + row * 256 + ((slot * 16) ^ ((row & 7) << 4))) = v;
        }
        // stage V^T (rows = d, 128B, swizzled)
        #pragma unroll
        for (int i = 0; i < 4; ++i) {
            int d = wave * 32 + i * 8 + (lane >> 3);
            int slot = lane & 7;
            bf16x8 v = *reinterpret_cast<const bf16x8*>(
                reinterpret_cast<const char*>(Vth + (size_t)d * S + kbase) + slot * 16);
            *reinterpret_cast<bf16x8*>(VtB + d * 128 + ((slot * 16) ^ ((d & 7) << 4))) = v;
        }
        __syncthreads();

        // QK^T -> p -> P strip (bf16)
        #pragma unroll
        for (int cg = 0; cg < 4; ++cg) {
            f32x4 acc = {0.f, 0.f, 0.f, 0.f};
            const int row = cg * 16 + lo;
            const int swzr = (row & 7) << 4;
            #pragma unroll
            for (int dc = 0; dc < 4; ++dc) {
                bf16x8 kf = *reinterpret_cast<const bf16x8*>(
                    KtB + row * 256 + ((hi * 16 + dc * 64) ^ swzr));
                acc = __builtin_amdgcn_mfma_f32_16x16x32_bf16(qf[dc], kf, acc, 0, 0, 0);
            }
            const int k = kbase + cg * 16 + lo;
            #pragma unroll
            for (int r = 0; r < 4; ++r) {
                const int q = qw0 + hi * 4 + r;
                float p = (k <= q) ? exp2f(acc[r]) * rcp[r] : 0.f;
                const int prow = hi * 4 + r;
                *reinterpret_cast<__bf16*>(
                    Ps + prow * 128 + ((2 * (cg * 16 + lo)) ^ ((prow & 7) << 4))) = (__bf16)p;
            }
        }

        // wide P + window stores (read strip back as b128)
        {
            const int row = lane >> 2;
            const int q = qw0 + row;
            float* dstP = out + O1 + ((size_t)h * S + q) * S + kbase;
            #pragma unroll
            for (int t = 0; t < 2; ++t) {
                int boff = (((lane & 3) * 16 + t * 64) ^ ((row & 7) << 4));
                bf16x8 pv8 = *reinterpret_cast<const bf16x8*>(Ps + row * 128 + boff);
                float4 f0 = {(float)pv8[0], (float)pv8[1], (float)pv8[2], (float)pv8[3]};
                float4 f1 = {(float)pv8[4], (float)pv8[5], (float)pv8[6], (float)pv8[7]};
                int k0 = (lane & 3) * 8 + t * 32;
                *reinterpret_cast<float4*>(dstP + k0) = f0;
                *reinterpret_cast<float4*>(dstP + k0 + 4) = f1;
                if (winrows) {
                    float* dstW = out + O2 + ((size_t)h * W + (q - W)) * S + kbase;
                    *reinterpret_cast<float4*>(dstW + k0) = f0;
                    *reinterpret_cast<float4*>(dstW + k0 + 4) = f1;
                }
            }
        }

        // PV accumulate
        #pragma unroll
        for (int kc = 0; kc < 2; ++kc) {
            const int cb = (kc * 64 + hi * 16) ^ ((lo & 7) << 4);
            bf16x8 pf = *reinterpret_cast<const bf16x8*>(Ps + lo * 128 + cb);
            #pragma unroll
            for (int dg = 0; dg < 8; ++dg) {
                const int d = dg * 16 + lo;
                bf16x8 vf = *reinterpret_cast<const bf16x8*>(VtB + d * 128 + cb);
                oacc[dg] = __builtin_amdgcn_mfma_f32_16x16x32_bf16(pf, vf, oacc[dg], 0, 0, 0);
            }
        }
    }

    // zero-fill masked tiles
    {
        const int r0 = tid >> 4;
        const int c4 = (tid & 15) * 4;
        const float4 z = {0.f, 0.f, 0.f, 0.f};
        for (int kt = qt + 1; kt < 32; ++kt) {
            const int kbase = kt << 6;
            #pragma unroll
            for (int i = 0; i < 4; ++i) {
                const int q = q0 + r0 + i * 16;
                *reinterpret_cast<float4*>(&out[O1 + ((size_t)h * S + q) * S + kbase + c4]) = z;
                if (winrows)
                    *reinterpret_cast<float4*>(&out[O2 + ((size_t)h * W + (q - W)) * S + kbase + c4]) = z;
            }
        }
    }

    // attn_output (S, HQ, D)
    #pragma unroll
    for (int dg = 0; dg < 8; ++dg) {
        #pragma unroll
        for (int r = 0; r < 4; ++r) {
            const int q = qw0 + hi * 4 + r;
            out[((size_t)q * HQ + h) * D + dg * 16 + lo] = oacc[dg][r];
        }
    }
}

extern "C" void kernel_launch(void* const* d_in, const int* in_sizes, int n_in,
                              void* d_out, int out_size, void* d_ws, size_t ws_size,
                              hipStream_t stream)
{
    const float* Q = (const float*)d_in[0];
    const float* K = (const float*)d_in[1];
    const float* V = (const float*)d_in[2];
    float* out = (float*)d_out;

    __bf16* Kb  = (__bf16*)d_ws;                                  // 4 MB
    __bf16* Vtb = (__bf16*)((char*)d_ws + (size_t)4 * 1024 * 1024); // 4 MB
    float*  lsr = (float*)((char*)d_ws + (size_t)8 * 1024 * 1024);  // 256 KB

    hipLaunchKernelGGL(prep_kernel, dim3(256),  dim3(256), 0, stream, K, V, Kb, Vtb);
    hipLaunchKernelGGL(lsum_kernel, dim3(1024), dim3(256), 0, stream, Q, Kb, lsr);
    hipLaunchKernelGGL(attn_main,   dim3(1024), dim3(256), 0, stream, Q, Kb, Vtb, lsr, out);
}

// Round 3
// 278.733 us; speedup vs baseline: 2.5603x; 1.4411x over previous
//
#include <hip/hip_runtime.h>
#include <hip/hip_bf16.h>

typedef __bf16 bf16x8 __attribute__((ext_vector_type(8)));
typedef float f32x4 __attribute__((ext_vector_type(4)));
static_assert(sizeof(bf16x8) == 16, "bf16x8 must be 16B");

constexpr int S = 2048, D = 128, HQ = 32, W = 1024;
constexpr float SCALE_L2E = 0.08838834764831845f * 1.4426950408889634f;

constexpr size_t O1 = (size_t)S * HQ * D;        // attn_weights offset
constexpr size_t O2 = O1 + (size_t)HQ * S * S;   // window offset
constexpr int TILE_BYTES = 64 * 256;             // 16 KB per tile image

// async 16B global->LDS copy (wave-uniform LDS base semantics; lane*16 applied by HW,
// we pass per-lane ptrs whose lane0 value equals the base, valid under either semantic)
__device__ __forceinline__ void gl_lds16(const void* g, void* l) {
    __builtin_amdgcn_global_load_lds(
        (const __attribute__((address_space(1))) void*)(unsigned long long)g,
        (__attribute__((address_space(3))) void*)(unsigned int)(unsigned long long)l,
        16, 0, 0);
}

// ---------------- prep: K,V -> bf16 pre-swizzled tile images in ws ----------------
__global__ __launch_bounds__(256)
void prep_kernel(const float* __restrict__ K, const float* __restrict__ V,
                 char* __restrict__ KbI, char* __restrict__ VtI)
{
    __shared__ __attribute__((aligned(16))) __bf16 Vs[128][72];
    const int b = blockIdx.x, hkv = b >> 5, kt = b & 31;
    const int tid = threadIdx.x;
    const float* Ks   = K + ((size_t)hkv * S + kt * 64) * D;
    const float* Vsrc = V + ((size_t)hkv * S + kt * 64) * D;
    char* Kimg = KbI + (size_t)(hkv * 32 + kt) * TILE_BYTES;
    char* Vimg = VtI + (size_t)(hkv * 32 + kt) * TILE_BYTES;

    // K image: [row 0..63][slot 0..15], byte = row*256 + (slot*16 ^ ((row&7)<<4))
    #pragma unroll
    for (int i = 0; i < 4; ++i) {
        int idx = tid + i * 256;
        int r = idx >> 4, sl = idx & 15;
        float4 a = *reinterpret_cast<const float4*>(Ks + r * D + sl * 8);
        float4 c = *reinterpret_cast<const float4*>(Ks + r * D + sl * 8 + 4);
        bf16x8 f = {(__bf16)a.x, (__bf16)a.y, (__bf16)a.z, (__bf16)a.w,
                    (__bf16)c.x, (__bf16)c.y, (__bf16)c.z, (__bf16)c.w};
        *reinterpret_cast<bf16x8*>(Kimg + r * 256 + ((sl * 16) ^ ((r & 7) << 4))) = f;
    }
    // V transpose via LDS
    #pragma unroll
    for (int i = 0; i < 8; ++i) {
        int idx = tid + i * 256;
        int r = idx >> 5, c = (idx & 31) * 4;
        float4 vv = *reinterpret_cast<const float4*>(Vsrc + r * D + c);
        Vs[c + 0][r] = (__bf16)vv.x; Vs[c + 1][r] = (__bf16)vv.y;
        Vs[c + 2][r] = (__bf16)vv.z; Vs[c + 3][r] = (__bf16)vv.w;
    }
    __syncthreads();
    // V image: [d 0..127][slot 0..7], byte = d*128 + (slot*16 ^ ((d&7)<<4))
    #pragma unroll
    for (int i = 0; i < 4; ++i) {
        int idx = tid + i * 256;
        int d = idx >> 3, sl = idx & 7;
        bf16x8 v = *reinterpret_cast<const bf16x8*>(&Vs[d][sl * 8]);
        *reinterpret_cast<bf16x8*>(Vimg + d * 128 + ((sl * 16) ^ ((d & 7) << 4))) = v;
    }
}

// ---------------- fused main: lsum pass + P/window stores + PV + O ----------------
__global__ __launch_bounds__(256, 2)
void attn_fused2(const float* __restrict__ Q, const char* __restrict__ KbI,
                 const char* __restrict__ VtI, float* __restrict__ out)
{
    __shared__ __attribute__((aligned(16))) char LDS_K[2][TILE_BYTES];  // 32 KB
    __shared__ __attribute__((aligned(16))) char LDS_V[2][TILE_BYTES];  // 32 KB
    __shared__ __attribute__((aligned(16))) char LDS_P[4][2048];        // 8 KB

    const int bid = blockIdx.x;
    const int h   = bid >> 5;
    const int qt  = 31 - (((bid & 31) + h) & 31);   // diagonal load balance
    const int hkv = h >> 2;
    const int q0  = qt << 6;
    const int tid = threadIdx.x, wave = tid >> 6, lane = tid & 63;
    const int lo = lane & 15, hi = lane >> 4;
    const int qw0 = q0 + wave * 16;
    const bool winrows = (q0 >= W);

    const char* Ktiles = KbI + (size_t)hkv * 32 * TILE_BYTES;
    const char* Vtiles = VtI + (size_t)hkv * 32 * TILE_BYTES;
    const float* Qh = Q + (size_t)h * S * D;

    // Q fragments (pre-scaled)
    bf16x8 qf[4];
    {
        const float* qs = Qh + (size_t)(qw0 + lo) * D + hi * 8;
        #pragma unroll
        for (int dc = 0; dc < 4; ++dc) {
            float4 a = *reinterpret_cast<const float4*>(qs + dc * 32);
            float4 b = *reinterpret_cast<const float4*>(qs + dc * 32 + 4);
            bf16x8 f;
            f[0] = (__bf16)(a.x * SCALE_L2E); f[1] = (__bf16)(a.y * SCALE_L2E);
            f[2] = (__bf16)(a.z * SCALE_L2E); f[3] = (__bf16)(a.w * SCALE_L2E);
            f[4] = (__bf16)(b.x * SCALE_L2E); f[5] = (__bf16)(b.y * SCALE_L2E);
            f[6] = (__bf16)(b.z * SCALE_L2E); f[7] = (__bf16)(b.w * SCALE_L2E);
            qf[dc] = f;
        }
    }

    // ================= phase A: row sums =================
    #pragma unroll
    for (int i = 0; i < 4; ++i)
        gl_lds16(Ktiles + (wave * 4 + i) * 1024 + lane * 16,
                 LDS_K[0] + (wave * 4 + i) * 1024);
    __builtin_amdgcn_sched_barrier(0);
    asm volatile("s_waitcnt vmcnt(0)" ::: "memory");
    __builtin_amdgcn_s_barrier();
    __builtin_amdgcn_sched_barrier(0);

    float lsum[4] = {0.f, 0.f, 0.f, 0.f};
    int cur = 0;
    for (int kt = 0; kt <= qt; ++kt) {
        if (kt < qt) {
            const char* src = Ktiles + (size_t)(kt + 1) * TILE_BYTES;
            #pragma unroll
            for (int i = 0; i < 4; ++i)
                gl_lds16(src + (wave * 4 + i) * 1024 + lane * 16,
                         LDS_K[cur ^ 1] + (wave * 4 + i) * 1024);
            __builtin_amdgcn_sched_barrier(0);
        }
        const char* KtB = LDS_K[cur];
        #pragma unroll
        for (int cg = 0; cg < 4; ++cg) {
            f32x4 acc = {0.f, 0.f, 0.f, 0.f};
            const int row = cg * 16 + lo, swzr = (row & 7) << 4;
            #pragma unroll
            for (int dc = 0; dc < 4; ++dc) {
                bf16x8 kf = *reinterpret_cast<const bf16x8*>(
                    KtB + row * 256 + ((hi * 16 + dc * 64) ^ swzr));
                acc = __builtin_amdgcn_mfma_f32_16x16x32_bf16(qf[dc], kf, acc, 0, 0, 0);
            }
            const int k = (kt << 6) + cg * 16 + lo;
            #pragma unroll
            for (int r = 0; r < 4; ++r) {
                int q = qw0 + hi * 4 + r;
                lsum[r] += (k <= q) ? exp2f(acc[r]) : 0.f;
            }
        }
        if (kt < qt) {
            asm volatile("s_waitcnt vmcnt(0)" ::: "memory");
            __builtin_amdgcn_s_barrier();
            __builtin_amdgcn_sched_barrier(0);
        }
        cur ^= 1;
    }
    float rcp_[4];
    #pragma unroll
    for (int r = 0; r < 4; ++r) {
        float v = lsum[r];
        v += __shfl_xor(v, 1); v += __shfl_xor(v, 2);
        v += __shfl_xor(v, 4); v += __shfl_xor(v, 8);
        rcp_[r] = 1.0f / v;
    }

    // ================= phase B =================
    __builtin_amdgcn_s_barrier();            // everyone done reading phase-A LDS
    #pragma unroll
    for (int i = 0; i < 4; ++i) {
        gl_lds16(Ktiles + (wave * 4 + i) * 1024 + lane * 16, LDS_K[0] + (wave * 4 + i) * 1024);
        gl_lds16(Vtiles + (wave * 4 + i) * 1024 + lane * 16, LDS_V[0] + (wave * 4 + i) * 1024);
    }
    __builtin_amdgcn_sched_barrier(0);
    asm volatile("s_waitcnt vmcnt(0)" ::: "memory");
    __builtin_amdgcn_s_barrier();
    __builtin_amdgcn_sched_barrier(0);

    f32x4 oacc[8];
    #pragma unroll
    for (int i = 0; i < 8; ++i) oacc[i] = (f32x4){0.f, 0.f, 0.f, 0.f};
    char* Ps = LDS_P[wave];
    cur = 0;

    for (int kt = 0; kt <= qt; ++kt) {
        if (kt < qt) {   // issue next-tile loads FIRST (counted by the end-of-iter vmcnt)
            const char* sk = Ktiles + (size_t)(kt + 1) * TILE_BYTES;
            const char* sv = Vtiles + (size_t)(kt + 1) * TILE_BYTES;
            #pragma unroll
            for (int i = 0; i < 4; ++i) {
                gl_lds16(sk + (wave * 4 + i) * 1024 + lane * 16, LDS_K[cur ^ 1] + (wave * 4 + i) * 1024);
                gl_lds16(sv + (wave * 4 + i) * 1024 + lane * 16, LDS_V[cur ^ 1] + (wave * 4 + i) * 1024);
            }
            __builtin_amdgcn_sched_barrier(0);
        }
        const char* KtB = LDS_K[cur];
        const char* VtB = LDS_V[cur];
        const int kbase = kt << 6;

        // QK^T -> p -> per-wave P strip (bf16)
        #pragma unroll
        for (int cg = 0; cg < 4; ++cg) {
            f32x4 acc = {0.f, 0.f, 0.f, 0.f};
            const int row = cg * 16 + lo, swzr = (row & 7) << 4;
            #pragma unroll
            for (int dc = 0; dc < 4; ++dc) {
                bf16x8 kf = *reinterpret_cast<const bf16x8*>(
                    KtB + row * 256 + ((hi * 16 + dc * 64) ^ swzr));
                acc = __builtin_amdgcn_mfma_f32_16x16x32_bf16(qf[dc], kf, acc, 0, 0, 0);
            }
            const int k = kbase + cg * 16 + lo;
            #pragma unroll
            for (int r = 0; r < 4; ++r) {
                const int q = qw0 + hi * 4 + r;
                float p = (k <= q) ? exp2f(acc[r]) * rcp_[r] : 0.f;
                const int prow = hi * 4 + r;
                *reinterpret_cast<__bf16*>(
                    Ps + prow * 128 + ((2 * (cg * 16 + lo)) ^ ((prow & 7) << 4))) = (__bf16)p;
            }
        }

        // wide P (+window) stores from strip readback
        {
            const int row = lane >> 2;
            const int q = qw0 + row;
            float* dstP = out + O1 + ((size_t)h * S + q) * S + kbase;
            #pragma unroll
            for (int t = 0; t < 2; ++t) {
                int boff = (((lane & 3) * 16 + t * 64) ^ ((row & 7) << 4));
                bf16x8 pv8 = *reinterpret_cast<const bf16x8*>(Ps + row * 128 + boff);
                float4 f0 = {(float)pv8[0], (float)pv8[1], (float)pv8[2], (float)pv8[3]};
                float4 f1 = {(float)pv8[4], (float)pv8[5], (float)pv8[6], (float)pv8[7]};
                int k0 = (lane & 3) * 8 + t * 32;
                *reinterpret_cast<float4*>(dstP + k0) = f0;
                *reinterpret_cast<float4*>(dstP + k0 + 4) = f1;
                if (winrows) {
                    float* dstW = out + O2 + ((size_t)h * W + (q - W)) * S + kbase;
                    *reinterpret_cast<float4*>(dstW + k0) = f0;
                    *reinterpret_cast<float4*>(dstW + k0 + 4) = f1;
                }
            }
        }

        // PV accumulate
        #pragma unroll
        for (int kc = 0; kc < 2; ++kc) {
            const int cb = (kc * 64 + hi * 16) ^ ((lo & 7) << 4);
            bf16x8 pf = *reinterpret_cast<const bf16x8*>(Ps + lo * 128 + cb);
            #pragma unroll
            for (int dg = 0; dg < 8; ++dg) {
                bf16x8 vf = *reinterpret_cast<const bf16x8*>(VtB + (dg * 16 + lo) * 128 + cb);
                oacc[dg] = __builtin_amdgcn_mfma_f32_16x16x32_bf16(pf, vf, oacc[dg], 0, 0, 0);
            }
        }

        if (kt < qt) {
            // 8 loads were issued first this iter, then 4 (or 8) stores:
            // vmcnt(4) guarantees all 8 loads landed without draining the newest stores.
            asm volatile("s_waitcnt vmcnt(4)" ::: "memory");
            __builtin_amdgcn_s_barrier();
            __builtin_amdgcn_sched_barrier(0);
        }
        cur ^= 1;
    }

    // zero-fill masked tiles
    {
        const int r0 = tid >> 4;
        const int c4 = (tid & 15) * 4;
        const float4 z = {0.f, 0.f, 0.f, 0.f};
        for (int kt = qt + 1; kt < 32; ++kt) {
            const int kbase = kt << 6;
            #pragma unroll
            for (int i = 0; i < 4; ++i) {
                const int q = q0 + r0 + i * 16;
                *reinterpret_cast<float4*>(&out[O1 + ((size_t)h * S + q) * S + kbase + c4]) = z;
                if (winrows)
                    *reinterpret_cast<float4*>(&out[O2 + ((size_t)h * W + (q - W)) * S + kbase + c4]) = z;
            }
        }
    }

    // attn_output (S, HQ, D)
    #pragma unroll
    for (int dg = 0; dg < 8; ++dg) {
        #pragma unroll
        for (int r = 0; r < 4; ++r) {
            const int q = qw0 + hi * 4 + r;
            out[((size_t)q * HQ + h) * D + dg * 16 + lo] = oacc[dg][r];
        }
    }
}

extern "C" void kernel_launch(void* const* d_in, const int* in_sizes, int n_in,
                              void* d_out, int out_size, void* d_ws, size_t ws_size,
                              hipStream_t stream)
{
    const float* Q = (const float*)d_in[0];
    const float* K = (const float*)d_in[1];
    const float* V = (const float*)d_in[2];
    float* out = (float*)d_out;

    char* KbI = (char*)d_ws;                                   // 4 MB tile images
    char* VtI = (char*)d_ws + (size_t)4 * 1024 * 1024;         // 4 MB tile images

    hipLaunchKernelGGL(prep_kernel, dim3(256),  dim3(256), 0, stream, K, V, KbI, VtI);
    hipLaunchKernelGGL(attn_fused2, dim3(1024), dim3(256), 0, stream, Q, KbI, VtI, out);
}

// Round 4
// 263.520 us; speedup vs baseline: 2.7082x; 1.0577x over previous
//
#include <hip/hip_runtime.h>
#include <hip/hip_bf16.h>

typedef __bf16 bf16x8 __attribute__((ext_vector_type(8)));
typedef float f32x4 __attribute__((ext_vector_type(4)));
static_assert(sizeof(bf16x8) == 16, "bf16x8 must be 16B");

constexpr int S = 2048, D = 128, HQ = 32, W = 1024;
constexpr float SCALE_L2E = 0.08838834764831845f * 1.4426950408889634f;

constexpr size_t O1 = (size_t)S * HQ * D;        // attn_weights offset
constexpr size_t O2 = O1 + (size_t)HQ * S * S;   // window offset
constexpr int TILE_BYTES = 64 * 256;             // 16 KB per tile image

__device__ __forceinline__ void gl_lds16(const void* g, void* l) {
    __builtin_amdgcn_global_load_lds(
        (const __attribute__((address_space(1))) void*)(unsigned long long)g,
        (__attribute__((address_space(3))) void*)(unsigned int)(unsigned long long)l,
        16, 0, 0);
}

// ---------------- prep: K,V -> bf16 pre-swizzled tile images in ws ----------------
__global__ __launch_bounds__(256)
void prep_kernel(const float* __restrict__ K, const float* __restrict__ V,
                 char* __restrict__ KbI, char* __restrict__ VtI)
{
    __shared__ __attribute__((aligned(16))) __bf16 Vs[128][72];
    const int b = blockIdx.x, hkv = b >> 5, kt = b & 31;
    const int tid = threadIdx.x;
    const float* Ks   = K + ((size_t)hkv * S + kt * 64) * D;
    const float* Vsrc = V + ((size_t)hkv * S + kt * 64) * D;
    char* Kimg = KbI + (size_t)(hkv * 32 + kt) * TILE_BYTES;
    char* Vimg = VtI + (size_t)(hkv * 32 + kt) * TILE_BYTES;

    #pragma unroll
    for (int i = 0; i < 4; ++i) {
        int idx = tid + i * 256;
        int r = idx >> 4, sl = idx & 15;
        float4 a = *reinterpret_cast<const float4*>(Ks + r * D + sl * 8);
        float4 c = *reinterpret_cast<const float4*>(Ks + r * D + sl * 8 + 4);
        bf16x8 f = {(__bf16)a.x, (__bf16)a.y, (__bf16)a.z, (__bf16)a.w,
                    (__bf16)c.x, (__bf16)c.y, (__bf16)c.z, (__bf16)c.w};
        *reinterpret_cast<bf16x8*>(Kimg + r * 256 + ((sl * 16) ^ ((r & 7) << 4))) = f;
    }
    #pragma unroll
    for (int i = 0; i < 8; ++i) {
        int idx = tid + i * 256;
        int r = idx >> 5, c = (idx & 31) * 4;
        float4 vv = *reinterpret_cast<const float4*>(Vsrc + r * D + c);
        Vs[c + 0][r] = (__bf16)vv.x; Vs[c + 1][r] = (__bf16)vv.y;
        Vs[c + 2][r] = (__bf16)vv.z; Vs[c + 3][r] = (__bf16)vv.w;
    }
    __syncthreads();
    #pragma unroll
    for (int i = 0; i < 4; ++i) {
        int idx = tid + i * 256;
        int d = idx >> 3, sl = idx & 7;
        bf16x8 v = *reinterpret_cast<const bf16x8*>(&Vs[d][sl * 8]);
        *reinterpret_cast<bf16x8*>(Vimg + d * 128 + ((sl * 16) ^ ((d & 7) << 4))) = v;
    }
}

// ------- fused main: paired q-row-blocks (qt1=16+p, qt2=15-p), 8 waves -------
__global__ __launch_bounds__(512, 4)
void attn_fused3(const float* __restrict__ Q, const char* __restrict__ KbI,
                 const char* __restrict__ VtI, float* __restrict__ out)
{
    __shared__ __attribute__((aligned(16))) char LDS_K[2][TILE_BYTES];  // 32 KB
    __shared__ __attribute__((aligned(16))) char LDS_V[2][TILE_BYTES];  // 32 KB
    __shared__ __attribute__((aligned(16))) char LDS_P[8][2048];        // 16 KB

    const int bid = blockIdx.x;
    const int h   = bid & 31;
    const int p   = bid >> 5;            // pair index 0..15
    const int qt1 = 16 + p;              // upper row-block (always window)
    const int qt2 = 15 - p;              // lower row-block (never window)
    const int hkv = h >> 2;
    const int tid = threadIdx.x, wave = tid >> 6, lane = tid & 63;
    const int lo = lane & 15, hi = lane >> 4;
    const int rg   = wave >> 2;          // 0 -> qt1 rows, 1 -> qt2 rows
    const int qt_r = rg ? qt2 : qt1;
    const int qw0  = (qt_r << 6) + (wave & 3) * 16;
    const bool winw = (rg == 0);

    const char* Ktiles = KbI + (size_t)hkv * 32 * TILE_BYTES;
    const char* Vtiles = VtI + (size_t)hkv * 32 * TILE_BYTES;
    const float* Qh = Q + (size_t)h * S * D;

    // Q fragments (pre-scaled)
    bf16x8 qf[4];
    {
        const float* qs = Qh + (size_t)(qw0 + lo) * D + hi * 8;
        #pragma unroll
        for (int dc = 0; dc < 4; ++dc) {
            float4 a = *reinterpret_cast<const float4*>(qs + dc * 32);
            float4 b = *reinterpret_cast<const float4*>(qs + dc * 32 + 4);
            bf16x8 f;
            f[0] = (__bf16)(a.x * SCALE_L2E); f[1] = (__bf16)(a.y * SCALE_L2E);
            f[2] = (__bf16)(a.z * SCALE_L2E); f[3] = (__bf16)(a.w * SCALE_L2E);
            f[4] = (__bf16)(b.x * SCALE_L2E); f[5] = (__bf16)(b.y * SCALE_L2E);
            f[6] = (__bf16)(b.z * SCALE_L2E); f[7] = (__bf16)(b.w * SCALE_L2E);
            qf[dc] = f;
        }
    }

    // ================= phase A: row sums (shared K staging, both rows) =========
    #pragma unroll
    for (int i = 0; i < 2; ++i)
        gl_lds16(Ktiles + (wave * 2 + i) * 1024 + lane * 16,
                 LDS_K[0] + (wave * 2 + i) * 1024);
    __builtin_amdgcn_sched_barrier(0);
    asm volatile("s_waitcnt vmcnt(0)" ::: "memory");
    __builtin_amdgcn_s_barrier();
    __builtin_amdgcn_sched_barrier(0);

    float lsum[4] = {0.f, 0.f, 0.f, 0.f};
    int cur = 0;
    for (int kt = 0; kt <= qt1; ++kt) {
        if (kt < qt1) {
            const char* src = Ktiles + (size_t)(kt + 1) * TILE_BYTES;
            #pragma unroll
            for (int i = 0; i < 2; ++i)
                gl_lds16(src + (wave * 2 + i) * 1024 + lane * 16,
                         LDS_K[cur ^ 1] + (wave * 2 + i) * 1024);
            __builtin_amdgcn_sched_barrier(0);
        }
        if (kt <= qt_r) {
            const char* KtB = LDS_K[cur];
            #pragma unroll
            for (int cg = 0; cg < 4; ++cg) {
                f32x4 acc = {0.f, 0.f, 0.f, 0.f};
                const int row = cg * 16 + lo, swzr = (row & 7) << 4;
                #pragma unroll
                for (int dc = 0; dc < 4; ++dc) {
                    bf16x8 kf = *reinterpret_cast<const bf16x8*>(
                        KtB + row * 256 + ((hi * 16 + dc * 64) ^ swzr));
                    acc = __builtin_amdgcn_mfma_f32_16x16x32_bf16(qf[dc], kf, acc, 0, 0, 0);
                }
                const int k = (kt << 6) + cg * 16 + lo;
                #pragma unroll
                for (int r = 0; r < 4; ++r) {
                    int q = qw0 + hi * 4 + r;
                    lsum[r] += (k <= q) ? exp2f(acc[r]) : 0.f;
                }
            }
        }
        if (kt < qt1) {
            asm volatile("s_waitcnt vmcnt(0)" ::: "memory");
            __builtin_amdgcn_s_barrier();
            __builtin_amdgcn_sched_barrier(0);
        }
        cur ^= 1;
    }
    float rcp_[4];
    #pragma unroll
    for (int r = 0; r < 4; ++r) {
        float v = lsum[r];
        v += __shfl_xor(v, 1); v += __shfl_xor(v, 2);
        v += __shfl_xor(v, 4); v += __shfl_xor(v, 8);
        rcp_[r] = 1.0f / v;
    }

    // ================= phase B =================
    __builtin_amdgcn_s_barrier();            // all phase-A LDS reads done
    #pragma unroll
    for (int i = 0; i < 2; ++i) {
        gl_lds16(Ktiles + (wave * 2 + i) * 1024 + lane * 16, LDS_K[0] + (wave * 2 + i) * 1024);
        gl_lds16(Vtiles + (wave * 2 + i) * 1024 + lane * 16, LDS_V[0] + (wave * 2 + i) * 1024);
    }
    __builtin_amdgcn_sched_barrier(0);
    asm volatile("s_waitcnt vmcnt(0)" ::: "memory");
    __builtin_amdgcn_s_barrier();
    __builtin_amdgcn_sched_barrier(0);

    f32x4 oacc[8];
    #pragma unroll
    for (int i = 0; i < 8; ++i) oacc[i] = (f32x4){0.f, 0.f, 0.f, 0.f};
    char* Ps = LDS_P[wave];
    cur = 0;

    for (int kt = 0; kt <= qt1; ++kt) {
        if (kt < qt1) {   // next-tile loads issued FIRST (drained by end-of-iter wait)
            const char* sk = Ktiles + (size_t)(kt + 1) * TILE_BYTES;
            const char* sv = Vtiles + (size_t)(kt + 1) * TILE_BYTES;
            #pragma unroll
            for (int i = 0; i < 2; ++i) {
                gl_lds16(sk + (wave * 2 + i) * 1024 + lane * 16, LDS_K[cur ^ 1] + (wave * 2 + i) * 1024);
                gl_lds16(sv + (wave * 2 + i) * 1024 + lane * 16, LDS_V[cur ^ 1] + (wave * 2 + i) * 1024);
            }
            __builtin_amdgcn_sched_barrier(0);
        }
        if (kt <= qt_r) {
            const char* KtB = LDS_K[cur];
            const char* VtB = LDS_V[cur];
            const int kbase = kt << 6;

            // QK^T -> p -> per-wave P strip (bf16)
            #pragma unroll
            for (int cg = 0; cg < 4; ++cg) {
                f32x4 acc = {0.f, 0.f, 0.f, 0.f};
                const int row = cg * 16 + lo, swzr = (row & 7) << 4;
                #pragma unroll
                for (int dc = 0; dc < 4; ++dc) {
                    bf16x8 kf = *reinterpret_cast<const bf16x8*>(
                        KtB + row * 256 + ((hi * 16 + dc * 64) ^ swzr));
                    acc = __builtin_amdgcn_mfma_f32_16x16x32_bf16(qf[dc], kf, acc, 0, 0, 0);
                }
                const int k = kbase + cg * 16 + lo;
                #pragma unroll
                for (int r = 0; r < 4; ++r) {
                    const int q = qw0 + hi * 4 + r;
                    float pv = (k <= q) ? exp2f(acc[r]) * rcp_[r] : 0.f;
                    const int prow = hi * 4 + r;
                    *reinterpret_cast<__bf16*>(
                        Ps + prow * 128 + ((2 * (cg * 16 + lo)) ^ ((prow & 7) << 4))) = (__bf16)pv;
                }
            }

            // wide P (+window) stores from strip readback
            {
                const int row = lane >> 2;
                const int q = qw0 + row;
                float* dstP = out + O1 + ((size_t)h * S + q) * S + kbase;
                #pragma unroll
                for (int t = 0; t < 2; ++t) {
                    int boff = (((lane & 3) * 16 + t * 64) ^ ((row & 7) << 4));
                    bf16x8 pv8 = *reinterpret_cast<const bf16x8*>(Ps + row * 128 + boff);
                    float4 f0 = {(float)pv8[0], (float)pv8[1], (float)pv8[2], (float)pv8[3]};
                    float4 f1 = {(float)pv8[4], (float)pv8[5], (float)pv8[6], (float)pv8[7]};
                    int k0 = (lane & 3) * 8 + t * 32;
                    *reinterpret_cast<float4*>(dstP + k0) = f0;
                    *reinterpret_cast<float4*>(dstP + k0 + 4) = f1;
                    if (winw) {
                        float* dstW = out + O2 + ((size_t)h * W + (q - W)) * S + kbase;
                        *reinterpret_cast<float4*>(dstW + k0) = f0;
                        *reinterpret_cast<float4*>(dstW + k0 + 4) = f1;
                    }
                }
            }

            // PV accumulate
            #pragma unroll
            for (int kc = 0; kc < 2; ++kc) {
                const int cb = (kc * 64 + hi * 16) ^ ((lo & 7) << 4);
                bf16x8 pf = *reinterpret_cast<const bf16x8*>(Ps + lo * 128 + cb);
                #pragma unroll
                for (int dg = 0; dg < 8; ++dg) {
                    bf16x8 vf = *reinterpret_cast<const bf16x8*>(VtB + (dg * 16 + lo) * 128 + cb);
                    oacc[dg] = __builtin_amdgcn_mfma_f32_16x16x32_bf16(pf, vf, oacc[dg], 0, 0, 0);
                }
            }
        }
        if (kt < qt1) {
            // per-wave outstanding at this point: 4 loads (oldest) + stores (newest).
            // rg0: 8 stores -> vmcnt(8); rg1 active: 4 stores -> vmcnt(4); rg1 idle: vmcnt(0).
            if (rg == 0)            asm volatile("s_waitcnt vmcnt(8)" ::: "memory");
            else if (kt <= qt2)     asm volatile("s_waitcnt vmcnt(4)" ::: "memory");
            else                    asm volatile("s_waitcnt vmcnt(0)" ::: "memory");
            __builtin_amdgcn_s_barrier();
            __builtin_amdgcn_sched_barrier(0);
        }
        cur ^= 1;
    }

    // zero-fill masked tiles (each wave fills its own 16 rows)
    {
        const int zr = lane >> 2;
        const int c0 = (lane & 3) * 16;
        const float4 z = {0.f, 0.f, 0.f, 0.f};
        const int q = qw0 + zr;
        for (int kt = qt_r + 1; kt < 32; ++kt) {
            float* dp = out + O1 + ((size_t)h * S + q) * S + kt * 64 + c0;
            #pragma unroll
            for (int j = 0; j < 4; ++j) *reinterpret_cast<float4*>(dp + j * 4) = z;
            if (winw) {
                float* dw = out + O2 + ((size_t)h * W + (q - W)) * S + kt * 64 + c0;
                #pragma unroll
                for (int j = 0; j < 4; ++j) *reinterpret_cast<float4*>(dw + j * 4) = z;
            }
        }
    }

    // attn_output (S, HQ, D)
    #pragma unroll
    for (int dg = 0; dg < 8; ++dg) {
        #pragma unroll
        for (int r = 0; r < 4; ++r) {
            const int q = qw0 + hi * 4 + r;
            out[((size_t)q * HQ + h) * D + dg * 16 + lo] = oacc[dg][r];
        }
    }
}

extern "C" void kernel_launch(void* const* d_in, const int* in_sizes, int n_in,
                              void* d_out, int out_size, void* d_ws, size_t ws_size,
                              hipStream_t stream)
{
    const float* Q = (const float*)d_in[0];
    const float* K = (const float*)d_in[1];
    const float* V = (const float*)d_in[2];
    float* out = (float*)d_out;

    char* KbI = (char*)d_ws;                                   // 4 MB tile images
    char* VtI = (char*)d_ws + (size_t)4 * 1024 * 1024;         // 4 MB tile images

    hipLaunchKernelGGL(prep_kernel, dim3(256), dim3(256), 0, stream, K, V, KbI, VtI);
    hipLaunchKernelGGL(attn_fused3, dim3(512), dim3(512), 0, stream, Q, KbI, VtI, out);
}